// Round 1
// baseline (465.501 us; speedup 1.0000x reference)
//
#include <hip/hip_runtime.h>
#include <stdint.h>

#define BB 8
#define NN 50000
#define CC 8
#define SCORE_THR 0.99f
#define NMS_THR 0.5f
#define MAX_DET 100
#define K_PRE 1024
#define CAP 2048
#define BCAP 8192

typedef unsigned long long u64;
typedef unsigned int u32;

// ws layout:
//   int cand_cnt[64]            @ 0
//   int kept_cnt[8]             @ 64*4
//   u64 cand_keys[64*CAP]       @ 512
//   u64 kept_keys[8*BCAP]       @ 512 + 64*CAP*8

__global__ void k_init(int* __restrict__ cnts) {
    int t = threadIdx.x;
    if (t < 72) cnts[t] = 0;
}

__global__ void k_filter(const float* __restrict__ cls,
                         int* __restrict__ cand_cnt,
                         u64* __restrict__ cand_keys) {
    int b = blockIdx.y;
    int n = blockIdx.x * blockDim.x + threadIdx.x;
    int lane = threadIdx.x & 63;
    bool vn = n < NN;
    float s[8];
    if (vn) {
        const float4* p = (const float4*)(cls + ((size_t)b * NN + n) * CC);
        float4 a = p[0], b2 = p[1];
        s[0] = a.x; s[1] = a.y; s[2] = a.z; s[3] = a.w;
        s[4] = b2.x; s[5] = b2.y; s[6] = b2.z; s[7] = b2.w;
    } else {
        #pragma unroll
        for (int c = 0; c < 8; ++c) s[c] = 0.f;
    }
    #pragma unroll
    for (int c = 0; c < 8; ++c) {
        bool pred = vn && (s[c] > SCORE_THR);
        u64 m = __ballot(pred);
        if (m) {
            int leader = __ffsll((unsigned long long)m) - 1;
            int base = 0;
            if (lane == leader) base = atomicAdd(&cand_cnt[b * 8 + c], (int)__popcll(m));
            base = __shfl(base, leader);
            if (pred) {
                int slot = base + (int)__popcll(m & ((1ull << lane) - 1ull));
                if (slot < CAP)
                    cand_keys[(size_t)(b * 8 + c) * CAP + slot] =
                        ((u64)__float_as_uint(s[c]) << 32) | (u32)(~(u32)n);
            }
        }
    }
}

__global__ __launch_bounds__(1024) void k_nms(const float* __restrict__ boxes,
                                              const int* __restrict__ cand_cnt,
                                              const u64* __restrict__ cand_keys,
                                              int* __restrict__ kept_cnt,
                                              u64* __restrict__ kept_keys) {
    __shared__ u64 sk[CAP];
    __shared__ float bx1[K_PRE], by1[K_PRE], bx2[K_PRE], by2[K_PRE], bar[K_PRE];
    __shared__ int keep[K_PRE];
    __shared__ int sup[64];
    int tid = threadIdx.x;
    int bc = blockIdx.x;
    int b = bc >> 3, c = bc & 7;
    int cnt = cand_cnt[bc];
    if (cnt > CAP) cnt = CAP;
    for (int i = tid; i < CAP; i += 1024)
        sk[i] = (i < cnt) ? cand_keys[(size_t)bc * CAP + i] : 0ull;
    // bitonic sort, descending (key = score_bits<<32 | ~n  -> score desc, idx asc)
    for (int k = 2; k <= CAP; k <<= 1)
        for (int j = k >> 1; j > 0; j >>= 1) {
            __syncthreads();
            for (int i = tid; i < CAP; i += 1024) {
                int ixj = i ^ j;
                if (ixj > i) {
                    u64 a = sk[i], b2 = sk[ixj];
                    bool desc = (i & k) == 0;
                    if (desc ? (a < b2) : (a > b2)) { sk[i] = b2; sk[ixj] = a; }
                }
            }
        }
    __syncthreads();
    int n_cand = cnt < K_PRE ? cnt : K_PRE;
    if (tid < K_PRE) {
        keep[tid] = 0;
        if (tid < n_cand) {
            u32 n = ~(u32)sk[tid];
            const float4 b4 = *(const float4*)(boxes + ((size_t)b * NN + n) * 4);
            bx1[tid] = b4.x; by1[tid] = b4.y; bx2[tid] = b4.z; by2[tid] = b4.w;
            bar[tid] = (b4.z - b4.x) * (b4.w - b4.y);
        }
    }
    __syncthreads();
    int ntiles = (n_cand + 63) >> 6;
    for (int t = 0; t < ntiles; ++t) {
        int s0 = t << 6;
        if (tid < 64) sup[tid] = 0;
        __syncthreads();
        {   // parallel: suppression of this tile by finalized kept candidates [0, s0)
            int jl = tid & 63, g = tid >> 6;
            int j = s0 + jl;
            if (j < n_cand) {
                float x1j = bx1[j], y1j = by1[j], x2j = bx2[j], y2j = by2[j], aj = bar[j];
                int part = 0;
                for (int i = g; i < s0; i += 16) {
                    if (keep[i]) {
                        float iw = fminf(x2j, bx2[i]) - fmaxf(x1j, bx1[i]);
                        float ih = fminf(y2j, by2[i]) - fmaxf(y1j, by1[i]);
                        iw = fmaxf(iw, 0.f); ih = fmaxf(ih, 0.f);
                        float inter = iw * ih;
                        float iou = inter / (aj + bar[i] - inter);
                        if (iou > NMS_THR) { part = 1; break; }
                    }
                }
                if (part) atomicOr(&sup[jl], 1);
            }
        }
        __syncthreads();
        if (tid < 64) {  // sequential in-wave resolution within the tile (wave 0)
            int j = s0 + tid;
            bool vj = j < n_cand;
            float x1j = vj ? bx1[j] : 0.f;
            float y1j = vj ? by1[j] : 0.f;
            float x2j = vj ? bx2[j] : 0.f;
            float y2j = vj ? by2[j] : 0.f;
            float aj  = vj ? bar[j] : 1.f;
            int supj = sup[tid];
            int keepj = 0;
            for (int k = 0; k < 64; ++k) {
                int supk = __shfl(supj, k);
                int kk = ((s0 + k) < n_cand) && !supk;
                if (tid == k) keepj = kk;
                if (kk) {
                    float x1k = __shfl(x1j, k);
                    float y1k = __shfl(y1j, k);
                    float x2k = __shfl(x2j, k);
                    float y2k = __shfl(y2j, k);
                    float ak  = __shfl(aj, k);
                    if (vj && tid > k) {
                        float iw = fminf(x2j, x2k) - fmaxf(x1j, x1k);
                        float ih = fminf(y2j, y2k) - fmaxf(y1j, y1k);
                        iw = fmaxf(iw, 0.f); ih = fmaxf(ih, 0.f);
                        float inter = iw * ih;
                        float iou = inter / (aj + ak - inter);
                        if (iou > NMS_THR) supj = 1;
                    }
                }
            }
            if (vj) keep[j] = keepj;
        }
        __syncthreads();
    }
    // append kept candidates to per-batch list
    bool pred = (tid < n_cand) && keep[tid];
    u64 fkey = 0;
    if (pred) {
        u64 key = sk[tid];
        u32 sb = (u32)(key >> 32);
        u32 n = (~(u32)key) & 0x1FFFFu;
        int pos = c * K_PRE + tid;   // index into the reference's [c*K_PRE] sc array
        fkey = ((u64)sb << 30) | ((u64)(8191 - pos) << 17) | (u64)n;
    }
    u64 m = __ballot(pred);
    if (m) {
        int lane = tid & 63;
        int leader = __ffsll((unsigned long long)m) - 1;
        int base = 0;
        if (lane == leader) base = atomicAdd(&kept_cnt[b], (int)__popcll(m));
        base = __shfl(base, leader);
        if (pred) {
            int slot = base + (int)__popcll(m & ((1ull << lane) - 1ull));
            kept_keys[(size_t)b * BCAP + slot] = fkey;
        }
    }
}

__global__ __launch_bounds__(1024) void k_final(const float* __restrict__ boxes,
                                                const float* __restrict__ rot,
                                                const float* __restrict__ trans,
                                                const int* __restrict__ kept_cnt,
                                                const u64* __restrict__ kept_keys,
                                                float* __restrict__ out) {
    __shared__ u64 fk[BCAP];   // 64 KiB
    int tid = threadIdx.x;
    int b = blockIdx.x;
    int cnt = kept_cnt[b];
    if (cnt > BCAP) cnt = BCAP;
    for (int i = tid; i < BCAP; i += 1024)
        fk[i] = (i < cnt) ? kept_keys[(size_t)b * BCAP + i] : 0ull;
    for (int k = 2; k <= BCAP; k <<= 1)
        for (int j = k >> 1; j > 0; j >>= 1) {
            __syncthreads();
            for (int i = tid; i < BCAP; i += 1024) {
                int ixj = i ^ j;
                if (ixj > i) {
                    u64 a = fk[i], b2 = fk[ixj];
                    bool desc = (i & k) == 0;
                    if (desc ? (a < b2) : (a > b2)) { fk[i] = b2; fk[ixj] = a; }
                }
            }
        }
    __syncthreads();
    if (tid < MAX_DET) {
        int kk = tid;
        bool ok = kk < cnt;
        float ob[4] = {-1.f, -1.f, -1.f, -1.f};
        float orr[3] = {-1.f, -1.f, -1.f};
        float otr[3] = {-1.f, -1.f, -1.f};
        float osc = -1.f, olb = -1.f;
        if (ok) {
            u64 key = fk[kk];
            u32 n = (u32)(key & 0x1FFFFu);
            int pos = 8191 - (int)((key >> 17) & 0x1FFFu);
            int cls = pos >> 10;
            osc = __uint_as_float((u32)(key >> 30));
            olb = (float)cls;
            const float* bp = boxes + ((size_t)b * NN + n) * 4;
            ob[0] = bp[0]; ob[1] = bp[1]; ob[2] = bp[2]; ob[3] = bp[3];
            const float* rp = rot + ((size_t)b * NN + n) * 3;
            orr[0] = rp[0]; orr[1] = rp[1]; orr[2] = rp[2];
            const float* tp = trans + ((size_t)b * NN + n) * 3;
            otr[0] = tp[0]; otr[1] = tp[1]; otr[2] = tp[2];
        }
        int base = b * MAX_DET + kk;
        out[base * 4 + 0] = ob[0];
        out[base * 4 + 1] = ob[1];
        out[base * 4 + 2] = ob[2];
        out[base * 4 + 3] = ob[3];
        out[BB * MAX_DET * 4 + base] = osc;          // scores @ 3200
        out[BB * MAX_DET * 5 + base] = olb;          // labels @ 4000
        float* ro = out + BB * MAX_DET * 6;          // rot @ 4800
        ro[base * 3 + 0] = orr[0];
        ro[base * 3 + 1] = orr[1];
        ro[base * 3 + 2] = orr[2];
        float* to = out + BB * MAX_DET * 6 + BB * MAX_DET * 3;  // trans @ 7200
        to[base * 3 + 0] = otr[0];
        to[base * 3 + 1] = otr[1];
        to[base * 3 + 2] = otr[2];
    }
}

extern "C" void kernel_launch(void* const* d_in, const int* in_sizes, int n_in,
                              void* d_out, int out_size, void* d_ws, size_t ws_size,
                              hipStream_t stream) {
    const float* boxes = (const float*)d_in[0];
    const float* cls   = (const float*)d_in[1];
    const float* rot   = (const float*)d_in[2];
    const float* trans = (const float*)d_in[3];
    int* cand_cnt = (int*)d_ws;
    int* kept_cnt = cand_cnt + 64;
    u64* cand_keys = (u64*)((char*)d_ws + 512);
    u64* kept_keys = (u64*)((char*)d_ws + 512 + (size_t)64 * CAP * 8);
    float* out = (float*)d_out;

    hipLaunchKernelGGL(k_init, dim3(1), dim3(128), 0, stream, cand_cnt);
    hipLaunchKernelGGL(k_filter, dim3((NN + 255) / 256, BB), dim3(256), 0, stream,
                       cls, cand_cnt, cand_keys);
    hipLaunchKernelGGL(k_nms, dim3(64), dim3(1024), 0, stream,
                       boxes, cand_cnt, cand_keys, kept_cnt, kept_keys);
    hipLaunchKernelGGL(k_final, dim3(BB), dim3(1024), 0, stream,
                       boxes, rot, trans, kept_cnt, kept_keys, out);
}

// Round 2
// 326.553 us; speedup vs baseline: 1.4255x; 1.4255x over previous
//
#include <hip/hip_runtime.h>
#include <stdint.h>

#define BB 8
#define NN 50000
#define CC 8
#define SCORE_THR 0.99f
#define NMS_THR 0.5f
#define MAX_DET 100
#define K_PRE 1024
#define CAP 2048
#define KEEP_CAP 128

typedef unsigned long long u64;
typedef unsigned int u32;

// ws layout:
//   int cand_cnt[64]              @ 0
//   int kept_cnt[64]              @ 256
//   u64 cand_keys[64*CAP]         @ 512
//   u64 kept_keys[64*KEEP_CAP]    @ 512 + 64*CAP*8

__global__ void k_init(int* __restrict__ cnts) {
    int t = threadIdx.x;
    if (t < 128) cnts[t] = 0;
}

__global__ void k_filter(const float* __restrict__ cls,
                         int* __restrict__ cand_cnt,
                         u64* __restrict__ cand_keys) {
    int b = blockIdx.y;
    int n = blockIdx.x * blockDim.x + threadIdx.x;
    int lane = threadIdx.x & 63;
    bool vn = n < NN;
    float s[8];
    if (vn) {
        const float4* p = (const float4*)(cls + ((size_t)b * NN + n) * CC);
        float4 a = p[0], b2 = p[1];
        s[0] = a.x; s[1] = a.y; s[2] = a.z; s[3] = a.w;
        s[4] = b2.x; s[5] = b2.y; s[6] = b2.z; s[7] = b2.w;
    } else {
        #pragma unroll
        for (int c = 0; c < 8; ++c) s[c] = 0.f;
    }
    #pragma unroll
    for (int c = 0; c < 8; ++c) {
        bool pred = vn && (s[c] > SCORE_THR);
        u64 m = __ballot(pred);
        if (m) {
            int leader = __ffsll((unsigned long long)m) - 1;
            int base = 0;
            if (lane == leader) base = atomicAdd(&cand_cnt[b * 8 + c], (int)__popcll(m));
            base = __shfl(base, leader);
            if (pred) {
                int slot = base + (int)__popcll(m & ((1ull << lane) - 1ull));
                if (slot < CAP)
                    cand_keys[(size_t)(b * 8 + c) * CAP + slot] =
                        ((u64)__float_as_uint(s[c]) << 32) | (u32)(~(u32)n);
            }
        }
    }
}

__global__ __launch_bounds__(1024) void k_nms(const float* __restrict__ boxes,
                                              const int* __restrict__ cand_cnt,
                                              const u64* __restrict__ cand_keys,
                                              int* __restrict__ kept_cnt,
                                              u64* __restrict__ kept_keys) {
    __shared__ u64 sk[CAP];
    __shared__ float bx1[K_PRE], by1[K_PRE], bx2[K_PRE], by2[K_PRE], bar[K_PRE];
    __shared__ int keep[K_PRE];
    __shared__ int sup[64];
    __shared__ u64 tmask[64];
    __shared__ int wsum[16];
    __shared__ int wpre[17];
    int tid = threadIdx.x;
    int bc = blockIdx.x;
    int c = bc & 7;
    int b = bc >> 3;
    int cnt = cand_cnt[bc];
    if (cnt > CAP) cnt = CAP;
    // sort 1024 when possible (always, for this distribution); 2048 fallback
    int SZ = (cnt <= K_PRE) ? K_PRE : CAP;
    for (int i = tid; i < SZ; i += 1024)
        sk[i] = (i < cnt) ? cand_keys[(size_t)bc * CAP + i] : 0ull;
    for (int k = 2; k <= SZ; k <<= 1)
        for (int j = k >> 1; j > 0; j >>= 1) {
            __syncthreads();
            for (int i = tid; i < SZ; i += 1024) {
                int ixj = i ^ j;
                if (ixj > i) {
                    u64 a = sk[i], b2 = sk[ixj];
                    bool desc = (i & k) == 0;
                    if (desc ? (a < b2) : (a > b2)) { sk[i] = b2; sk[ixj] = a; }
                }
            }
        }
    __syncthreads();
    int n_cand = cnt < K_PRE ? cnt : K_PRE;
    if (tid < K_PRE) {
        keep[tid] = 0;
        if (tid < n_cand) {
            u32 n = ~(u32)sk[tid];
            const float4 b4 = *(const float4*)(boxes + ((size_t)b * NN + n) * 4);
            bx1[tid] = b4.x; by1[tid] = b4.y; bx2[tid] = b4.z; by2[tid] = b4.w;
            bar[tid] = (b4.z - b4.x) * (b4.w - b4.y);
        }
    }
    __syncthreads();
    int lane = tid & 63, w = tid >> 6;
    int ntiles = (n_cand + 63) >> 6;
    for (int t = 0; t < ntiles; ++t) {
        int s0 = t << 6;
        if (tid < 64) sup[tid] = 0;
        __syncthreads();
        // 1) parallel: suppression of tile candidates by finalized keeps [0, s0)
        {
            int j = s0 + lane;
            int part = 0;
            if (j < n_cand) {
                float x1j = bx1[j], y1j = by1[j], x2j = bx2[j], y2j = by2[j], aj = bar[j];
                for (int i = w; i < s0; i += 16) {
                    if (keep[i]) {
                        float iw = fminf(x2j, bx2[i]) - fmaxf(x1j, bx1[i]);
                        float ih = fminf(y2j, by2[i]) - fmaxf(y1j, by1[i]);
                        iw = fmaxf(iw, 0.f); ih = fmaxf(ih, 0.f);
                        float inter = iw * ih;
                        float iou = inter / (aj + bar[i] - inter);
                        if (iou > NMS_THR) { part = 1; break; }
                    }
                }
            }
            if (part) atomicOr(&sup[lane], 1);
        }
        // 2) parallel: 64x64 in-tile IoU bit matrix (wave w -> rows w, w+16, w+32, w+48)
        #pragma unroll
        for (int r = 0; r < 4; ++r) {
            int jj = w + 16 * r;        // in-tile row
            int j = s0 + jj;
            int i2 = s0 + lane;         // in-tile col
            bool p = false;
            if (j < n_cand && i2 < n_cand && lane < jj) {
                float iw = fminf(bx2[j], bx2[i2]) - fmaxf(bx1[j], bx1[i2]);
                float ih = fminf(by2[j], by2[i2]) - fmaxf(by1[j], by1[i2]);
                iw = fmaxf(iw, 0.f); ih = fmaxf(ih, 0.f);
                float inter = iw * ih;
                float iou = inter / (bar[j] + bar[i2] - inter);
                p = iou > NMS_THR;
            }
            u64 m = __ballot(p);
            if (lane == 0) tmask[jj] = m;
        }
        __syncthreads();
        // 3) serial greedy scan over 64 bitmask rows (one thread)
        if (tid == 0) {
            u64 kb = 0;
            int nmax = n_cand - s0; if (nmax > 64) nmax = 64;
            for (int j = 0; j < nmax; ++j) {
                int kp = (!sup[j]) && ((tmask[j] & kb) == 0ull);
                keep[s0 + j] = kp;
                if (kp) kb |= (1ull << j);
            }
        }
        __syncthreads();
    }
    // ordered compaction of kept candidates (first KEEP_CAP per class)
    bool kp = (tid < n_cand) && keep[tid];
    u64 bal = __ballot(kp);
    if (lane == 0) wsum[w] = (int)__popcll(bal);
    __syncthreads();
    if (tid == 0) {
        int acc = 0;
        for (int i = 0; i < 16; ++i) { wpre[i] = acc; acc += wsum[i]; }
        wpre[16] = acc;
        kept_cnt[bc] = acc < KEEP_CAP ? acc : KEEP_CAP;
    }
    __syncthreads();
    if (kp) {
        int rank = wpre[w] + (int)__popcll(bal & ((1ull << lane) - 1ull));
        if (rank < KEEP_CAP) {
            u64 key = sk[tid];
            u32 sb = (u32)(key >> 32);
            u32 n = (~(u32)key) & 0x1FFFFu;
            int pos = c * K_PRE + tid;  // position in the reference's [c*K_PRE] sc array
            kept_keys[(size_t)bc * KEEP_CAP + rank] =
                ((u64)sb << 30) | ((u64)(8191 - pos) << 17) | (u64)n;
        }
    }
}

__global__ __launch_bounds__(1024) void k_final(const float* __restrict__ boxes,
                                                const float* __restrict__ rot,
                                                const float* __restrict__ trans,
                                                const int* __restrict__ kept_cnt,
                                                const u64* __restrict__ kept_keys,
                                                float* __restrict__ out) {
    __shared__ u64 fk[1024];
    int tid = threadIdx.x;
    int b = blockIdx.x;
    int c = tid >> 7, i = tid & 127;
    int cc2 = kept_cnt[b * 8 + c];
    fk[tid] = (i < cc2) ? kept_keys[(size_t)(b * 8 + c) * KEEP_CAP + i] : 0ull;
    for (int k = 2; k <= 1024; k <<= 1)
        for (int j = k >> 1; j > 0; j >>= 1) {
            __syncthreads();
            int ixj = tid ^ j;
            if (ixj > tid) {
                u64 a = fk[tid], b2 = fk[ixj];
                bool desc = (tid & k) == 0;
                if (desc ? (a < b2) : (a > b2)) { fk[tid] = b2; fk[ixj] = a; }
            }
        }
    __syncthreads();
    if (tid < MAX_DET) {
        u64 key = fk[tid];
        bool ok = key != 0ull;
        float ob[4] = {-1.f, -1.f, -1.f, -1.f};
        float orr[3] = {-1.f, -1.f, -1.f};
        float otr[3] = {-1.f, -1.f, -1.f};
        float osc = -1.f, olb = -1.f;
        if (ok) {
            u32 n = (u32)(key & 0x1FFFFu);
            int pos = 8191 - (int)((key >> 17) & 0x1FFFu);
            int cls = pos >> 10;
            osc = __uint_as_float((u32)(key >> 30));
            olb = (float)cls;
            const float* bp = boxes + ((size_t)b * NN + n) * 4;
            ob[0] = bp[0]; ob[1] = bp[1]; ob[2] = bp[2]; ob[3] = bp[3];
            const float* rp = rot + ((size_t)b * NN + n) * 3;
            orr[0] = rp[0]; orr[1] = rp[1]; orr[2] = rp[2];
            const float* tp = trans + ((size_t)b * NN + n) * 3;
            otr[0] = tp[0]; otr[1] = tp[1]; otr[2] = tp[2];
        }
        int base = b * MAX_DET + tid;
        out[base * 4 + 0] = ob[0];
        out[base * 4 + 1] = ob[1];
        out[base * 4 + 2] = ob[2];
        out[base * 4 + 3] = ob[3];
        out[BB * MAX_DET * 4 + base] = osc;          // scores @ 3200
        out[BB * MAX_DET * 5 + base] = olb;          // labels @ 4000
        float* ro = out + BB * MAX_DET * 6;          // rot @ 4800
        ro[base * 3 + 0] = orr[0];
        ro[base * 3 + 1] = orr[1];
        ro[base * 3 + 2] = orr[2];
        float* to = out + BB * MAX_DET * 6 + BB * MAX_DET * 3;  // trans @ 7200
        to[base * 3 + 0] = otr[0];
        to[base * 3 + 1] = otr[1];
        to[base * 3 + 2] = otr[2];
    }
}

extern "C" void kernel_launch(void* const* d_in, const int* in_sizes, int n_in,
                              void* d_out, int out_size, void* d_ws, size_t ws_size,
                              hipStream_t stream) {
    const float* boxes = (const float*)d_in[0];
    const float* cls   = (const float*)d_in[1];
    const float* rot   = (const float*)d_in[2];
    const float* trans = (const float*)d_in[3];
    int* cand_cnt = (int*)d_ws;
    int* kept_cnt = cand_cnt + 64;
    u64* cand_keys = (u64*)((char*)d_ws + 512);
    u64* kept_keys = (u64*)((char*)d_ws + 512 + (size_t)64 * CAP * 8);
    float* out = (float*)d_out;

    hipLaunchKernelGGL(k_init, dim3(1), dim3(128), 0, stream, cand_cnt);
    hipLaunchKernelGGL(k_filter, dim3((NN + 255) / 256, BB), dim3(256), 0, stream,
                       cls, cand_cnt, cand_keys);
    hipLaunchKernelGGL(k_nms, dim3(64), dim3(1024), 0, stream,
                       boxes, cand_cnt, cand_keys, kept_cnt, kept_keys);
    hipLaunchKernelGGL(k_final, dim3(BB), dim3(1024), 0, stream,
                       boxes, rot, trans, kept_cnt, kept_keys, out);
}

// Round 3
// 202.875 us; speedup vs baseline: 2.2945x; 1.6096x over previous
//
#include <hip/hip_runtime.h>
#include <stdint.h>

#define BB 8
#define NN 50000
#define SCORE_THR 0.99f
#define NMS_THR 0.5f
#define MAX_DET 100
#define K_PRE 1024
#define CAP 2048
#define KEEP_CAP 128
#define CNT_STRIDE 64   // ints => 256 B per counter, one counter per cache line

typedef unsigned long long u64;
typedef unsigned int u32;

// ws layout:
//   int cand_cnt[64*CNT_STRIDE]   @ 0           (16 KB, padded counters)
//   int kept_cnt[64]              @ 16384
//   u64 cand_keys[64*CAP]         @ 16896
//   u64 kept_keys[64*KEEP_CAP]    @ 16896 + 64*CAP*8

__global__ void k_init(int* __restrict__ cnts) {
    for (int i = threadIdx.x; i < 64 * CNT_STRIDE + 64; i += 256) cnts[i] = 0;
}

__global__ __launch_bounds__(256) void k_filter(const float* __restrict__ cls,
                                                int* __restrict__ cand_cnt,
                                                u64* __restrict__ cand_keys) {
    __shared__ int wcnt[8][4];
    __shared__ int woff[8][4];
    __shared__ int cbase[8];
    int b = blockIdx.y;
    int tid = threadIdx.x;
    int lane = tid & 63, w = tid >> 6;
    int n = blockIdx.x * 256 + tid;
    bool vn = n < NN;
    float s[8];
    if (vn) {
        const float4* p = (const float4*)(cls + ((size_t)b * NN + n) * 8);
        float4 a = p[0], b2 = p[1];
        s[0] = a.x; s[1] = a.y; s[2] = a.z; s[3] = a.w;
        s[4] = b2.x; s[5] = b2.y; s[6] = b2.z; s[7] = b2.w;
    } else {
        #pragma unroll
        for (int c = 0; c < 8; ++c) s[c] = 0.f;
    }
    u64 bal[8];
    #pragma unroll
    for (int c = 0; c < 8; ++c) {
        bool pred = vn && (s[c] > SCORE_THR);
        bal[c] = __ballot(pred);
        if (lane == 0) wcnt[c][w] = (int)__popcll(bal[c]);
    }
    __syncthreads();
    if (tid < 8) {
        int c = tid, acc = 0;
        #pragma unroll
        for (int ww = 0; ww < 4; ++ww) { woff[c][ww] = acc; acc += wcnt[c][ww]; }
        cbase[c] = acc ? atomicAdd(&cand_cnt[(b * 8 + c) * CNT_STRIDE], acc) : 0;
    }
    __syncthreads();
    #pragma unroll
    for (int c = 0; c < 8; ++c) {
        if (vn && (s[c] > SCORE_THR)) {
            int slot = cbase[c] + woff[c][w] + (int)__popcll(bal[c] & ((1ull << lane) - 1ull));
            if (slot < CAP)
                cand_keys[(size_t)(b * 8 + c) * CAP + slot] =
                    ((u64)__float_as_uint(s[c]) << 32) | (u32)(~(u32)n);
        }
    }
}

__global__ __launch_bounds__(1024) void k_nms(const float* __restrict__ boxes,
                                              const int* __restrict__ cand_cnt,
                                              const u64* __restrict__ cand_keys,
                                              int* __restrict__ kept_cnt,
                                              u64* __restrict__ kept_keys) {
    __shared__ u64 sk[CAP];
    __shared__ float bx1[K_PRE], by1[K_PRE], bx2[K_PRE], by2[K_PRE], bar[K_PRE];
    __shared__ int keep[K_PRE];
    __shared__ int sup[K_PRE];
    __shared__ u64 tmask[64];
    __shared__ u64 kbs;
    __shared__ int wsum[16];
    __shared__ int wpre[17];
    int tid = threadIdx.x;
    int bc = blockIdx.x;
    int c = bc & 7;
    int b = bc >> 3;
    int lane = tid & 63, w = tid >> 6;
    int cnt = cand_cnt[bc * CNT_STRIDE];
    if (cnt > CAP) cnt = CAP;
    int SZ = (cnt <= K_PRE) ? K_PRE : CAP;
    for (int i = tid; i < SZ; i += 1024)
        sk[i] = (i < cnt) ? cand_keys[(size_t)bc * CAP + i] : 0ull;
    for (int k = 2; k <= SZ; k <<= 1)
        for (int j = k >> 1; j > 0; j >>= 1) {
            __syncthreads();
            for (int i = tid; i < SZ; i += 1024) {
                int ixj = i ^ j;
                if (ixj > i) {
                    u64 a = sk[i], b2 = sk[ixj];
                    bool desc = (i & k) == 0;
                    if (desc ? (a < b2) : (a > b2)) { sk[i] = b2; sk[ixj] = a; }
                }
            }
        }
    __syncthreads();
    int n_cand = cnt < K_PRE ? cnt : K_PRE;
    // load own box to registers + LDS
    float x1 = 0.f, y1 = 0.f, x2 = 0.f, y2 = 0.f, ar = 1.f;
    keep[tid] = 0;
    sup[tid] = 0;
    if (tid < n_cand) {
        u32 n = ~(u32)sk[tid];
        const float4 b4 = *(const float4*)(boxes + ((size_t)b * NN + n) * 4);
        x1 = b4.x; y1 = b4.y; x2 = b4.z; y2 = b4.w;
        ar = (x2 - x1) * (y2 - y1);
        bx1[tid] = x1; by1[tid] = y1; bx2[tid] = x2; by2[tid] = y2; bar[tid] = ar;
    }
    __syncthreads();
    int ntiles = (n_cand + 63) >> 6;
    for (int t = 0; t < ntiles; ++t) {
        int s0 = t << 6;
        // 1) parallel 64x64 in-tile IoU bit matrix (wave w -> rows w,w+16,w+32,w+48)
        #pragma unroll
        for (int r = 0; r < 4; ++r) {
            int jj = w + 16 * r;
            int j = s0 + jj;
            int i2 = s0 + lane;
            bool p = false;
            if (j < n_cand && lane < jj) {
                float iw = fminf(bx2[j], bx2[i2]) - fmaxf(bx1[j], bx1[i2]);
                float ih = fminf(by2[j], by2[i2]) - fmaxf(by1[j], by1[i2]);
                iw = fmaxf(iw, 0.f); ih = fmaxf(ih, 0.f);
                float inter = iw * ih;
                float iou = inter / (bar[j] + bar[i2] - inter);
                p = iou > NMS_THR;
            }
            u64 m = __ballot(p);
            if (lane == 0) tmask[jj] = m;
        }
        __syncthreads();
        // 2) wave-0 in-register greedy over the tile (alive-mask trick)
        if (w == 0) {
            int nmax = n_cand - s0; if (nmax > 64) nmax = 64;
            u64 rowmask = tmask[lane];
            int el = (lane < nmax) && (sup[s0 + lane] == 0);
            u64 alive = __ballot(el != 0);
            u64 kb = 0;
            while (alive) {
                int j = __ffsll(alive) - 1;
                kb |= (1ull << j);
                u64 colj = __ballot(((rowmask >> j) & 1ull) != 0);
                alive &= ~(colj | (1ull << j));
            }
            keep[s0 + lane] = (int)((kb >> lane) & 1ull);
            if (lane == 0) kbs = kb;
        }
        __syncthreads();
        // 3) parallel forward suppression: later candidates vs kept-in-tile
        {
            u64 kb = kbs;
            int j2 = tid;
            if (j2 >= s0 + 64 && j2 < n_cand && sup[j2] == 0 && kb) {
                u64 m = kb;
                int supped = 0;
                while (m) {
                    int k = __ffsll(m) - 1; m &= m - 1ull;
                    int i = s0 + k;
                    float iw = fminf(x2, bx2[i]) - fmaxf(x1, bx1[i]);
                    float ih = fminf(y2, by2[i]) - fmaxf(y1, by1[i]);
                    iw = fmaxf(iw, 0.f); ih = fmaxf(ih, 0.f);
                    float inter = iw * ih;
                    float iou = inter / (ar + bar[i] - inter);
                    if (iou > NMS_THR) { supped = 1; break; }
                }
                if (supped) sup[j2] = 1;
            }
        }
        __syncthreads();
    }
    // ordered compaction of kept candidates (first KEEP_CAP per class)
    bool kp = (tid < n_cand) && keep[tid];
    u64 bal = __ballot(kp);
    if (lane == 0) wsum[w] = (int)__popcll(bal);
    __syncthreads();
    if (tid == 0) {
        int acc = 0;
        for (int i = 0; i < 16; ++i) { wpre[i] = acc; acc += wsum[i]; }
        wpre[16] = acc;
        kept_cnt[bc] = acc < KEEP_CAP ? acc : KEEP_CAP;
    }
    __syncthreads();
    if (kp) {
        int rank = wpre[w] + (int)__popcll(bal & ((1ull << lane) - 1ull));
        if (rank < KEEP_CAP) {
            u64 key = sk[tid];
            u32 sb = (u32)(key >> 32);
            u32 n = (~(u32)key) & 0x1FFFFu;
            int pos = c * K_PRE + tid;  // position in the reference's [c*K_PRE] sc array
            kept_keys[(size_t)bc * KEEP_CAP + rank] =
                ((u64)sb << 30) | ((u64)(8191 - pos) << 17) | (u64)n;
        }
    }
}

__global__ __launch_bounds__(1024) void k_final(const float* __restrict__ boxes,
                                                const float* __restrict__ rot,
                                                const float* __restrict__ trans,
                                                const int* __restrict__ kept_cnt,
                                                const u64* __restrict__ kept_keys,
                                                float* __restrict__ out) {
    __shared__ u64 fk[1024];
    int tid = threadIdx.x;
    int b = blockIdx.x;
    int c = tid >> 7, i = tid & 127;
    int cc2 = kept_cnt[b * 8 + c];
    u64 key = (i < cc2) ? kept_keys[(size_t)(b * 8 + c) * KEEP_CAP + i] : 0ull;
    // per-class runs are already sorted descending; reverse odd runs -> alternating
    // desc/asc runs of 128, then only the last 3 bitonic merge stages are needed.
    int dst = (c & 1) ? (c * 128 + (127 - i)) : (c * 128 + i);
    fk[dst] = key;
    for (int k = 256; k <= 1024; k <<= 1)
        for (int j = k >> 1; j > 0; j >>= 1) {
            __syncthreads();
            int ixj = tid ^ j;
            if (ixj > tid) {
                u64 a = fk[tid], b2 = fk[ixj];
                bool desc = (tid & k) == 0;
                if (desc ? (a < b2) : (a > b2)) { fk[tid] = b2; fk[ixj] = a; }
            }
        }
    __syncthreads();
    if (tid < MAX_DET) {
        u64 kk = fk[tid];
        bool ok = kk != 0ull;
        float ob[4] = {-1.f, -1.f, -1.f, -1.f};
        float orr[3] = {-1.f, -1.f, -1.f};
        float otr[3] = {-1.f, -1.f, -1.f};
        float osc = -1.f, olb = -1.f;
        if (ok) {
            u32 n = (u32)(kk & 0x1FFFFu);
            int pos = 8191 - (int)((kk >> 17) & 0x1FFFu);
            int cls = pos >> 10;
            osc = __uint_as_float((u32)(kk >> 30));
            olb = (float)cls;
            const float* bp = boxes + ((size_t)b * NN + n) * 4;
            ob[0] = bp[0]; ob[1] = bp[1]; ob[2] = bp[2]; ob[3] = bp[3];
            const float* rp = rot + ((size_t)b * NN + n) * 3;
            orr[0] = rp[0]; orr[1] = rp[1]; orr[2] = rp[2];
            const float* tp = trans + ((size_t)b * NN + n) * 3;
            otr[0] = tp[0]; otr[1] = tp[1]; otr[2] = tp[2];
        }
        int base = b * MAX_DET + tid;
        out[base * 4 + 0] = ob[0];
        out[base * 4 + 1] = ob[1];
        out[base * 4 + 2] = ob[2];
        out[base * 4 + 3] = ob[3];
        out[BB * MAX_DET * 4 + base] = osc;          // scores @ 3200
        out[BB * MAX_DET * 5 + base] = olb;          // labels @ 4000
        float* ro = out + BB * MAX_DET * 6;          // rot @ 4800
        ro[base * 3 + 0] = orr[0];
        ro[base * 3 + 1] = orr[1];
        ro[base * 3 + 2] = orr[2];
        float* to = out + BB * MAX_DET * 6 + BB * MAX_DET * 3;  // trans @ 7200
        to[base * 3 + 0] = otr[0];
        to[base * 3 + 1] = otr[1];
        to[base * 3 + 2] = otr[2];
    }
}

extern "C" void kernel_launch(void* const* d_in, const int* in_sizes, int n_in,
                              void* d_out, int out_size, void* d_ws, size_t ws_size,
                              hipStream_t stream) {
    const float* boxes = (const float*)d_in[0];
    const float* cls   = (const float*)d_in[1];
    const float* rot   = (const float*)d_in[2];
    const float* trans = (const float*)d_in[3];
    int* cand_cnt = (int*)d_ws;
    int* kept_cnt = cand_cnt + 64 * CNT_STRIDE;
    u64* cand_keys = (u64*)((char*)d_ws + 16896);
    u64* kept_keys = (u64*)((char*)d_ws + 16896 + (size_t)64 * CAP * 8);
    float* out = (float*)d_out;

    hipLaunchKernelGGL(k_init, dim3(1), dim3(256), 0, stream, cand_cnt);
    hipLaunchKernelGGL(k_filter, dim3((NN + 255) / 256, BB), dim3(256), 0, stream,
                       cls, cand_cnt, cand_keys);
    hipLaunchKernelGGL(k_nms, dim3(64), dim3(1024), 0, stream,
                       boxes, cand_cnt, cand_keys, kept_cnt, kept_keys);
    hipLaunchKernelGGL(k_final, dim3(BB), dim3(1024), 0, stream,
                       boxes, rot, trans, kept_cnt, kept_keys, out);
}